// Round 3
// baseline (392.007 us; speedup 1.0000x reference)
//
#include <hip/hip_runtime.h>
#include <stdint.h>

#define D_MODEL 1024
#define NHEAD 16
#define HEAD_DIM 64
#define SEQ 2048
#define BATCH 2
#define MROWS (BATCH*SEQ)   // 4096

typedef unsigned short u16;
typedef short bf16x8 __attribute__((ext_vector_type(8)));
typedef float f32x4 __attribute__((ext_vector_type(4)));

__device__ inline float bf2f(u16 h){ return __uint_as_float(((unsigned)h)<<16); }
__device__ inline u16 f2bf(float x){
  unsigned u = __float_as_uint(x);
  unsigned r = (u + 0x7FFFu + ((u>>16)&1u)) >> 16;
  return (u16)r;
}
// round-half-up bf16 (1 fewer VALU op; <=1ulp same class as RN) — P only
__device__ inline u16 f2bf_fast(float x){
  return (u16)((__float_as_uint(x) + 0x8000u) >> 16);
}

// Builtin MFMA: compiler's hazard recognizer inserts the MFMA->VALU nops
// that inline asm silently skipped (R2 failure root cause).
__device__ inline f32x4 mfma_bf16(bf16x8 a, bf16x8 b, f32x4 c){
  return __builtin_amdgcn_mfma_f32_16x16x32_bf16(a, b, c, 0, 0, 0);
}

__device__ inline void gld_lds16(const u16* g, u16* l){
  __builtin_amdgcn_global_load_lds(
      (const __attribute__((address_space(1))) void*)g,
      (__attribute__((address_space(3))) void*)l, 16, 0, 0);
}

// ---------------- pack kernels ----------------
__global__ __launch_bounds__(256) void pack_split(const float* __restrict__ src,
                                                  u16* __restrict__ hi, u16* __restrict__ lo, int n4){
  int i = blockIdx.x*256 + threadIdx.x;
  if (i >= n4) return;
  float4 v = ((const float4*)src)[i];
  float vv[4] = {v.x, v.y, v.z, v.w};
  u16 h[4], l[4];
  #pragma unroll
  for (int j=0;j<4;j++){
    h[j] = f2bf(vv[j]);
    l[j] = f2bf(vv[j] - bf2f(h[j]));
  }
  ((ushort4*)hi)[i] = make_ushort4(h[0],h[1],h[2],h[3]);
  ((ushort4*)lo)[i] = make_ushort4(l[0],l[1],l[2],l[3]);
}

__global__ __launch_bounds__(256) void pack_bias(const float* __restrict__ bq, const float* __restrict__ bk,
                                                 const float* __restrict__ bv, float* __restrict__ out){
  int i = blockIdx.x*256 + threadIdx.x;
  if (i < 1024) out[i] = bq[i];
  else if (i < 2048) out[i] = bk[i-1024];
  else if (i < 3072) out[i] = bv[i-2048];
}

// ---------------- GEMM: C = A * B^T (+bias), split-bf16 phases ----------------
template<int PHASES, int MODE>
__global__ __launch_bounds__(256) void gemm_bt(
    const u16* __restrict__ a_hi, const u16* __restrict__ a_lo,
    const u16* __restrict__ b_hi, const u16* __restrict__ b_lo,
    const float* __restrict__ bias,
    float* __restrict__ out_f,
    u16* __restrict__ qb, u16* __restrict__ kb, u16* __restrict__ vb,
    const float* __restrict__ gq, const float* __restrict__ gk,
    int M, int N, int K)
{
  __shared__ u16 lds[2][8192];   // per buf: A[128][32] then B[128][32]
  const int tid = threadIdx.x;
  const int lane = tid & 63;
  const int w = tid >> 6;
  const int wr = w >> 1, wc = w & 1;
  const int m0 = blockIdx.x * 128;
  const int n0 = blockIdx.y * 128;
  const int KS = K / 32;
  const int NT = PHASES * KS;

  f32x4 acc[4][4];
  #pragma unroll
  for (int i=0;i<4;i++)
    #pragma unroll
    for (int j=0;j<4;j++) acc[i][j] = (f32x4){0.f,0.f,0.f,0.f};

  auto stage = [&](int buf, int kt){
    int ph = (PHASES==1) ? 0 : (kt / KS);
    int kk = (PHASES==1 ? kt : (kt % KS)) * 32;
    const u16* As = (ph==1) ? a_lo : a_hi;
    const u16* Bs = (ph==2) ? b_lo : b_hi;
    u16* base = &lds[buf][0];
    #pragma unroll
    for (int r=0;r<2;r++){
      const u16* g = As + (size_t)(m0 + (tid>>2) + r*64)*K + kk + (tid&3)*8;
      gld_lds16(g, base + w*512 + r*2048);
    }
    #pragma unroll
    for (int r=0;r<2;r++){
      const u16* g = Bs + (size_t)(n0 + (tid>>2) + r*64)*K + kk + (tid&3)*8;
      gld_lds16(g, base + 4096 + w*512 + r*2048);
    }
  };

  auto compute = [&](int buf){
    const u16* la = &lds[buf][0];
    const u16* lb = &lds[buf][4096];
    const int koff = (lane>>4)*8;
    const int rowa = wr*64 + (lane&15);
    const int rowb = wc*64 + (lane&15);
    bf16x8 af[4], bfv[4];
    #pragma unroll
    for (int i=0;i<4;i++) af[i]  = *(const bf16x8*)&la[(rowa + i*16)*32 + koff];
    #pragma unroll
    for (int i=0;i<4;i++) bfv[i] = *(const bf16x8*)&lb[(rowb + i*16)*32 + koff];
    #pragma unroll
    for (int i=0;i<4;i++)
      #pragma unroll
      for (int j=0;j<4;j++)
        acc[i][j] = mfma_bf16(af[i], bfv[j], acc[i][j]);
  };

  stage(0, 0);
  for (int kt=0; kt<NT; ++kt){
    __syncthreads();
    if (kt+1 < NT) stage((kt+1)&1, kt+1);
    compute(kt&1);
  }

  const int gcolbase = n0 + wc*64;
  if (MODE == 0){
    #pragma unroll
    for (int j=0;j<4;j++){
      float bj = bias ? bias[gcolbase + j*16 + (lane&15)] : 0.f;
      #pragma unroll
      for (int i=0;i<4;i++){
        int row = m0 + wr*64 + i*16 + (lane>>4)*4;
        #pragma unroll
        for (int r=0;r<4;r++)
          out_f[(size_t)(row+r)*N + gcolbase + j*16 + (lane&15)] = acc[i][j][r] + bj;
      }
    }
  } else {
    const int sidx = gcolbase >> 6;   // 0..47 head-segment
    const int ttype = sidx < 16 ? 0 : (sidx < 32 ? 1 : 2);
    u16* dst = ttype==0 ? qb : (ttype==1 ? kb : vb);
    const int h = sidx - (ttype==1 ? 16 : (ttype==2 ? 32 : 0));
    float gvals[4], bvals[4];
    #pragma unroll
    for (int j=0;j<4;j++){
      int dh = j*16 + (lane&15);
      bvals[j] = bias[gcolbase + dh];
      gvals[j] = ttype==0 ? gq[dh] : (ttype==1 ? gk[dh] : 1.0f);
    }
    #pragma unroll
    for (int i=0;i<4;i++){
      #pragma unroll
      for (int r=0;r<4;r++){
        float tv[4];
        float ssq = 0.f;
        #pragma unroll
        for (int j=0;j<4;j++){ tv[j] = acc[i][j][r] + bvals[j]; ssq += tv[j]*tv[j]; }
        ssq += __shfl_xor(ssq, 1);
        ssq += __shfl_xor(ssq, 2);
        ssq += __shfl_xor(ssq, 4);
        ssq += __shfl_xor(ssq, 8);
        float s = 1.0f;
        if (ttype < 2) s = 1.0f / sqrtf(ssq * (1.0f/64.0f) + 1e-6f);
        int row = m0 + wr*64 + i*16 + (lane>>4)*4 + r;
        int bi = row >> 11, li = row & 2047;
        size_t obase = ((size_t)(bi*NHEAD + h)*SEQ + li)*HEAD_DIM;
        #pragma unroll
        for (int j=0;j<4;j++){
          float val = tv[j] * s * gvals[j];
          float z = rintf(val * 2.0f);           // round-half-even == jnp.round
          z = fminf(8.0f, fmaxf(-8.0f, z));
          dst[obase + j*16 + (lane&15)] = f2bf(z * 0.5f);   // exact in bf16
        }
      }
    }
  }
}

// ---------------- v [B,H,L,64] -> vT [B,H,64,L] ----------------
__global__ __launch_bounds__(256) void transpose_v(const u16* __restrict__ v, u16* __restrict__ vt){
  __shared__ u16 tl[64][66];
  int bh = blockIdx.x >> 5;
  int l0 = (blockIdx.x & 31) * 64;
  int tid = threadIdx.x;
  #pragma unroll
  for (int it=0; it<2; ++it){
    int idx = tid + it*256;
    int row = idx >> 3, g = idx & 7;
    bf16x8 d = *(const bf16x8*)(v + ((size_t)bh*SEQ + l0 + row)*64 + g*8);
    #pragma unroll
    for (int j=0;j<8;j++) tl[row][g*8+j] = (u16)d[j];
  }
  __syncthreads();
  #pragma unroll
  for (int it=0; it<2; ++it){
    int idx = tid + it*256;
    int dh = idx >> 3, g = idx & 7;
    u16 tmp[8];
    #pragma unroll
    for (int j=0;j<8;j++) tmp[j] = tl[g*8+j][dh];
    *(bf16x8*)(vt + ((size_t)bh*HEAD_DIM + dh)*SEQ + l0 + g*8) = *(const bf16x8*)tmp;
  }
}

// ---------------- flash attention (v2 structure, builtin MFMA) ----------------
// K/V read directly from global (L2-resident per head); only per-wave P in LDS.
// No __syncthreads: 4 independent waves per block.
__global__ __launch_bounds__(256) void attn_kernel(
    const u16* __restrict__ qb, const u16* __restrict__ kb, const u16* __restrict__ vt,
    u16* __restrict__ attn_out)
{
  __shared__ u16 lds_p[4][32*128];   // per-wave P, swizzled (32 KB total)
  const int tid = threadIdx.x, lane = tid & 63, w = tid >> 6;
  const int bh = blockIdx.y;
  const int q0 = blockIdx.x * 128;
  const size_t kvbase = (size_t)bh * SEQ * HEAD_DIM;
  const size_t vtbase = (size_t)bh * HEAD_DIM * SEQ;

  const int l15 = lane & 15;
  const int lq  = lane >> 4;          // quadrant 0..3
  const int swz_r = (l15 & 7) ^ (((l15 >> 3) & 1) * 3);   // swz3 of read-row (lane&15)
  const int swz_w = ((lq*4) & 7);     // partial: write row = mf*16 + lq*4 + r

  // Q fragments with softmax scale 0.125 folded in (exact: power of 2)
  bf16x8 qf[2][2];
  #pragma unroll
  for (int mf=0; mf<2; mf++)
    #pragma unroll
    for (int ks=0; ks<2; ks++){
      const u16* g = qb + kvbase + (size_t)(q0 + w*32 + mf*16 + l15)*64 + ks*32 + lq*8;
      bf16x8 v = *(const bf16x8*)g;
      #pragma unroll
      for (int j=0;j<8;j++) ((u16*)&v)[j] = f2bf(bf2f((u16)v[j]) * 0.125f);
      qf[mf][ks] = v;
    }

  float m_s[2][4], l_s[2][4];
  f32x4 o[2][4];
  #pragma unroll
  for (int mf=0;mf<2;mf++)
    #pragma unroll
    for (int r=0;r<4;r++){ m_s[mf][r] = -3.0e38f; l_s[mf][r] = 0.f; }
  #pragma unroll
  for (int mf=0;mf<2;mf++)
    #pragma unroll
    for (int nv=0;nv<4;nv++) o[mf][nv] = (f32x4){0.f,0.f,0.f,0.f};

  // global base pointers for this wave's fragment reads
  const u16* kbase = kb + kvbase + (size_t)l15*64 + lq*8;        // + kv*64 + ks*32
  const u16* vbase = vt + vtbase + (size_t)l15*SEQ + lq*8;       // + rowv*SEQ + kv0 + ks*32

  for (int t=0; t<16; ++t){
    const int kv0 = t*128;

    // ---- S = Q K^T (exact, K-frags direct from global/L2) ----
    f32x4 s[2][8];
    #pragma unroll
    for (int nf=0; nf<8; nf++){
      const u16* krow = kbase + (size_t)(kv0 + nf*16)*64;
      bf16x8 k0 = *(const bf16x8*)(krow);
      bf16x8 k1 = *(const bf16x8*)(krow + 32);
      s[0][nf] = mfma_bf16(qf[0][0], k0, (f32x4){0.f,0.f,0.f,0.f});
      s[1][nf] = mfma_bf16(qf[1][0], k0, (f32x4){0.f,0.f,0.f,0.f});
      s[0][nf] = mfma_bf16(qf[0][1], k1, s[0][nf]);
      s[1][nf] = mfma_bf16(qf[1][1], k1, s[1][nf]);
    }

    // ---- online softmax (per (mf,r): 4 q-rows reduced in parallel over 16 lanes) ----
    #pragma unroll
    for (int mf=0;mf<2;mf++){
      #pragma unroll
      for (int r=0;r<4;r++){
        float vmax = s[mf][0][r];
        #pragma unroll
        for (int nf=1;nf<8;nf++) vmax = fmaxf(vmax, s[mf][nf][r]);
        vmax = fmaxf(vmax, __shfl_xor(vmax,1));
        vmax = fmaxf(vmax, __shfl_xor(vmax,2));
        vmax = fmaxf(vmax, __shfl_xor(vmax,4));
        vmax = fmaxf(vmax, __shfl_xor(vmax,8));
        float mnew = fmaxf(m_s[mf][r], vmax);
        float c = __expf(m_s[mf][r] - mnew);
        float rsum = 0.f;
        #pragma unroll
        for (int nf=0;nf<8;nf++){
          float p = __expf(s[mf][nf][r] - mnew);
          s[mf][nf][r] = p;
          rsum += p;
        }
        rsum += __shfl_xor(rsum,1);
        rsum += __shfl_xor(rsum,2);
        rsum += __shfl_xor(rsum,4);
        rsum += __shfl_xor(rsum,8);
        l_s[mf][r] = l_s[mf][r]*c + rsum;
        m_s[mf][r] = mnew;
        #pragma unroll
        for (int nv=0;nv<4;nv++) o[mf][nv][r] *= c;
      }
    }

    // ---- P -> per-wave LDS (bf16, swizzled) ----
    #pragma unroll
    for (int mf=0;mf<2;mf++)
      #pragma unroll
      for (int nf=0;nf<8;nf++)
        #pragma unroll
        for (int r=0;r<4;r++){
          int rowp = mf*16 + lq*4 + r;
          int col  = nf*16 + l15;
          int sw   = ((swz_w + r) & 7) ^ ((lq >> 1) * 3);   // swz3(rowp)
          int slot = (col>>3) ^ sw;
          lds_p[w][rowp*128 + slot*8 + (col&7)] = f2bf_fast(s[mf][nf][r]);
        }

    // ---- O += P V (V-frags direct from global/L2, P from LDS) ----
    #pragma unroll
    for (int ks=0;ks<4;ks++){
      bf16x8 pa[2];
      #pragma unroll
      for (int mf=0;mf<2;mf++){
        int rowp = mf*16 + l15;
        int grp  = (ks*4 + lq) ^ swz_r;
        pa[mf] = *(const bf16x8*)&lds_p[w][rowp*128 + grp*8];
      }
      #pragma unroll
      for (int nv=0;nv<4;nv++){
        const u16* vrow = vbase + (size_t)(nv*16)*SEQ + kv0 + ks*32;
        bf16x8 vbv = *(const bf16x8*)vrow;
        o[0][nv] = mfma_bf16(pa[0], vbv, o[0][nv]);
        o[1][nv] = mfma_bf16(pa[1], vbv, o[1][nv]);
      }
    }
  }

  const int b = bh >> 4, h = bh & 15;
  #pragma unroll
  for (int mf=0;mf<2;mf++){
    #pragma unroll
    for (int r=0;r<4;r++){
      float inv = 1.0f / l_s[mf][r];
      int row = q0 + w*32 + mf*16 + lq*4 + r;
      size_t obase = ((size_t)b*SEQ + row)*D_MODEL + h*64;
      #pragma unroll
      for (int nv=0;nv<4;nv++)
        attn_out[obase + nv*16 + l15] = f2bf(o[mf][nv][r] * inv);
    }
  }
}

// ---------------- host ----------------
extern "C" void kernel_launch(void* const* d_in, const int* in_sizes, int n_in,
                              void* d_out, int out_size, void* d_ws, size_t ws_size,
                              hipStream_t stream){
  const float* x  = (const float*)d_in[0];
  const float* wq = (const float*)d_in[1];
  const float* bq = (const float*)d_in[2];
  const float* wk = (const float*)d_in[3];
  const float* bk = (const float*)d_in[4];
  const float* wv = (const float*)d_in[5];
  const float* bv = (const float*)d_in[6];
  const float* wo = (const float*)d_in[7];
  const float* bo = (const float*)d_in[8];
  const float* gq = (const float*)d_in[9];
  const float* gk = (const float*)d_in[10];
  float* out = (float*)d_out;

  char* ws = (char*)d_ws;
  size_t off = 0;
  auto alloc = [&](size_t bytes) -> char* {
    char* p = ws + off; off += (bytes + 255) & ~(size_t)255; return p;
  };
  const size_t ND = (size_t)MROWS * D_MODEL;       // 4M
  u16* x_hi    = (u16*)alloc(ND*2);
  u16* x_lo    = (u16*)alloc(ND*2);
  u16* wqkv_hi = (u16*)alloc((size_t)3072*1024*2);
  u16* wqkv_lo = (u16*)alloc((size_t)3072*1024*2);
  u16* wo_hi   = (u16*)alloc((size_t)1024*1024*2);
  u16* wo_lo   = (u16*)alloc((size_t)1024*1024*2);
  float* bqkv  = (float*)alloc(3072*4);
  u16* q_bf    = (u16*)alloc(ND*2);
  u16* k_bf    = (u16*)alloc(ND*2);
  u16* v_bf    = (u16*)alloc(ND*2);
  u16* vT      = (u16*)alloc(ND*2);
  u16* attn_bf = (u16*)alloc(ND*2);
  (void)ws_size; (void)in_sizes; (void)n_in; (void)out_size;

  pack_split<<<4096, 256, 0, stream>>>(x,  x_hi, x_lo, (int)(ND/4));
  pack_split<<<1024, 256, 0, stream>>>(wq, wqkv_hi,           wqkv_lo,           262144);
  pack_split<<<1024, 256, 0, stream>>>(wk, wqkv_hi + 1048576, wqkv_lo + 1048576, 262144);
  pack_split<<<1024, 256, 0, stream>>>(wv, wqkv_hi + 2097152, wqkv_lo + 2097152, 262144);
  pack_split<<<1024, 256, 0, stream>>>(wo, wo_hi, wo_lo, 262144);
  pack_bias<<<12, 256, 0, stream>>>(bq, bk, bv, bqkv);

  gemm_bt<3,1><<<dim3(32,24), 256, 0, stream>>>(x_hi, x_lo, wqkv_hi, wqkv_lo, bqkv,
        nullptr, q_bf, k_bf, v_bf, gq, gk, MROWS, 3072, 1024);

  transpose_v<<<1024, 256, 0, stream>>>(v_bf, vT);

  attn_kernel<<<dim3(16,32), 256, 0, stream>>>(q_bf, k_bf, vT, attn_bf);

  gemm_bt<1,0><<<dim3(32,8), 256, 0, stream>>>(attn_bf, nullptr, wo_hi, nullptr, bo,
        out, nullptr, nullptr, nullptr, nullptr, nullptr, MROWS, 1024, 1024);
}

// Round 4
// 242.510 us; speedup vs baseline: 1.6165x; 1.6165x over previous
//
#include <hip/hip_runtime.h>
#include <stdint.h>

#define D_MODEL 1024
#define NHEAD 16
#define HEAD_DIM 64
#define SEQ 2048
#define BATCH 2
#define MROWS (BATCH*SEQ)   // 4096
#define KVBLK 64
#define KVTILES (SEQ/KVBLK) // 32

typedef unsigned short u16;
typedef short bf16x8 __attribute__((ext_vector_type(8)));
typedef float f32x4 __attribute__((ext_vector_type(4)));

__device__ inline float bf2f(u16 h){ return __uint_as_float(((unsigned)h)<<16); }
__device__ inline u16 f2bf(float x){
  unsigned u = __float_as_uint(x);
  unsigned r = (u + 0x7FFFu + ((u>>16)&1u)) >> 16;
  return (u16)r;
}
// round-half-up bf16 (P only; <=1ulp class)
__device__ inline u16 f2bf_fast(float x){
  return (u16)((__float_as_uint(x) + 0x8000u) >> 16);
}

// Builtin MFMA: compiler inserts MFMA hazard nops/waitcnts (R2 lesson).
__device__ inline f32x4 mfma_bf16(bf16x8 a, bf16x8 b, f32x4 c){
  return __builtin_amdgcn_mfma_f32_16x16x32_bf16(a, b, c, 0, 0, 0);
}

__device__ inline void gld_lds16(const u16* g, u16* l){
  __builtin_amdgcn_global_load_lds(
      (const __attribute__((address_space(1))) void*)g,
      (__attribute__((address_space(3))) void*)l, 16, 0, 0);
}

// unified LDS swizzle: distinct per row within 8-row AND across 8-row stripes
__device__ inline int swz8(int row){ return (row ^ (row >> 3)) & 7; }

// ---------------- pack kernels ----------------
__global__ __launch_bounds__(256) void pack_split(const float* __restrict__ src,
                                                  u16* __restrict__ hi, u16* __restrict__ lo, int n4){
  int i = blockIdx.x*256 + threadIdx.x;
  if (i >= n4) return;
  float4 v = ((const float4*)src)[i];
  float vv[4] = {v.x, v.y, v.z, v.w};
  u16 h[4], l[4];
  #pragma unroll
  for (int j=0;j<4;j++){
    h[j] = f2bf(vv[j]);
    l[j] = f2bf(vv[j] - bf2f(h[j]));
  }
  ((ushort4*)hi)[i] = make_ushort4(h[0],h[1],h[2],h[3]);
  ((ushort4*)lo)[i] = make_ushort4(l[0],l[1],l[2],l[3]);
}

__global__ __launch_bounds__(256) void pack_bias(const float* __restrict__ bq, const float* __restrict__ bk,
                                                 const float* __restrict__ bv, float* __restrict__ out){
  int i = blockIdx.x*256 + threadIdx.x;
  if (i < 1024) out[i] = bq[i];
  else if (i < 2048) out[i] = bk[i-1024];
  else if (i < 3072) out[i] = bv[i-2048];
}

// ---------------- GEMM: C = A * B^T (+bias), split-bf16 phases ----------------
template<int PHASES, int MODE>
__global__ __launch_bounds__(256) void gemm_bt(
    const u16* __restrict__ a_hi, const u16* __restrict__ a_lo,
    const u16* __restrict__ b_hi, const u16* __restrict__ b_lo,
    const float* __restrict__ bias,
    float* __restrict__ out_f,
    u16* __restrict__ qb, u16* __restrict__ kb, u16* __restrict__ vb,
    const float* __restrict__ gq, const float* __restrict__ gk,
    int M, int N, int K)
{
  __shared__ u16 lds[2][8192];   // per buf: A[128][32] then B[128][32]
  const int tid = threadIdx.x;
  const int lane = tid & 63;
  const int w = tid >> 6;
  const int wr = w >> 1, wc = w & 1;
  const int m0 = blockIdx.x * 128;
  const int n0 = blockIdx.y * 128;
  const int KS = K / 32;
  const int NT = PHASES * KS;

  f32x4 acc[4][4];
  #pragma unroll
  for (int i=0;i<4;i++)
    #pragma unroll
    for (int j=0;j<4;j++) acc[i][j] = (f32x4){0.f,0.f,0.f,0.f};

  auto stage = [&](int buf, int kt){
    int ph = (PHASES==1) ? 0 : (kt / KS);
    int kk = (PHASES==1 ? kt : (kt % KS)) * 32;
    const u16* As = (ph==1) ? a_lo : a_hi;
    const u16* Bs = (ph==2) ? b_lo : b_hi;
    u16* base = &lds[buf][0];
    #pragma unroll
    for (int r=0;r<2;r++){
      const u16* g = As + (size_t)(m0 + (tid>>2) + r*64)*K + kk + (tid&3)*8;
      gld_lds16(g, base + w*512 + r*2048);
    }
    #pragma unroll
    for (int r=0;r<2;r++){
      const u16* g = Bs + (size_t)(n0 + (tid>>2) + r*64)*K + kk + (tid&3)*8;
      gld_lds16(g, base + 4096 + w*512 + r*2048);
    }
  };

  auto compute = [&](int buf){
    const u16* la = &lds[buf][0];
    const u16* lb = &lds[buf][4096];
    const int koff = (lane>>4)*8;
    const int rowa = wr*64 + (lane&15);
    const int rowb = wc*64 + (lane&15);
    bf16x8 af[4], bfv[4];
    #pragma unroll
    for (int i=0;i<4;i++) af[i]  = *(const bf16x8*)&la[(rowa + i*16)*32 + koff];
    #pragma unroll
    for (int i=0;i<4;i++) bfv[i] = *(const bf16x8*)&lb[(rowb + i*16)*32 + koff];
    #pragma unroll
    for (int i=0;i<4;i++)
      #pragma unroll
      for (int j=0;j<4;j++)
        acc[i][j] = mfma_bf16(af[i], bfv[j], acc[i][j]);
  };

  stage(0, 0);
  for (int kt=0; kt<NT; ++kt){
    __syncthreads();
    if (kt+1 < NT) stage((kt+1)&1, kt+1);
    compute(kt&1);
  }

  const int gcolbase = n0 + wc*64;
  if (MODE == 0){
    #pragma unroll
    for (int j=0;j<4;j++){
      float bj = bias ? bias[gcolbase + j*16 + (lane&15)] : 0.f;
      #pragma unroll
      for (int i=0;i<4;i++){
        int row = m0 + wr*64 + i*16 + (lane>>4)*4;
        #pragma unroll
        for (int r=0;r<4;r++)
          out_f[(size_t)(row+r)*N + gcolbase + j*16 + (lane&15)] = acc[i][j][r] + bj;
      }
    }
  } else {
    const int sidx = gcolbase >> 6;   // 0..47 head-segment
    const int ttype = sidx < 16 ? 0 : (sidx < 32 ? 1 : 2);
    u16* dst = ttype==0 ? qb : (ttype==1 ? kb : vb);
    const int h = sidx - (ttype==1 ? 16 : (ttype==2 ? 32 : 0));
    float gvals[4], bvals[4];
    #pragma unroll
    for (int j=0;j<4;j++){
      int dh = j*16 + (lane&15);
      bvals[j] = bias[gcolbase + dh];
      gvals[j] = ttype==0 ? gq[dh] : (ttype==1 ? gk[dh] : 1.0f);
    }
    #pragma unroll
    for (int i=0;i<4;i++){
      #pragma unroll
      for (int r=0;r<4;r++){
        float tv[4];
        float ssq = 0.f;
        #pragma unroll
        for (int j=0;j<4;j++){ tv[j] = acc[i][j][r] + bvals[j]; ssq += tv[j]*tv[j]; }
        ssq += __shfl_xor(ssq, 1);
        ssq += __shfl_xor(ssq, 2);
        ssq += __shfl_xor(ssq, 4);
        ssq += __shfl_xor(ssq, 8);
        float s = 1.0f;
        if (ttype < 2) s = 1.0f / sqrtf(ssq * (1.0f/64.0f) + 1e-6f);
        int row = m0 + wr*64 + i*16 + (lane>>4)*4 + r;
        int bi = row >> 11, li = row & 2047;
        size_t obase = ((size_t)(bi*NHEAD + h)*SEQ + li)*HEAD_DIM;
        #pragma unroll
        for (int j=0;j<4;j++){
          float val = tv[j] * s * gvals[j];
          float z = rintf(val * 2.0f);           // round-half-even == jnp.round
          z = fminf(8.0f, fmaxf(-8.0f, z));
          dst[obase + j*16 + (lane&15)] = f2bf(z * 0.5f);   // exact in bf16
        }
      }
    }
  }
}

// ---------------- v [B,H,L,64] -> vT [B,H,64,L] ----------------
__global__ __launch_bounds__(256) void transpose_v(const u16* __restrict__ v, u16* __restrict__ vt){
  __shared__ u16 tl[64][66];
  int bh = blockIdx.x >> 5;
  int l0 = (blockIdx.x & 31) * 64;
  int tid = threadIdx.x;
  #pragma unroll
  for (int it=0; it<2; ++it){
    int idx = tid + it*256;
    int row = idx >> 3, g = idx & 7;
    bf16x8 d = *(const bf16x8*)(v + ((size_t)bh*SEQ + l0 + row)*64 + g*8);
    #pragma unroll
    for (int j=0;j<8;j++) tl[row][g*8+j] = (u16)d[j];
  }
  __syncthreads();
  #pragma unroll
  for (int it=0; it<2; ++it){
    int idx = tid + it*256;
    int dh = idx >> 3, g = idx & 7;
    u16 tmp[8];
    #pragma unroll
    for (int j=0;j<8;j++) tmp[j] = tl[g*8+j][dh];
    *(bf16x8*)(vt + ((size_t)bh*HEAD_DIM + dh)*SEQ + l0 + g*8) = *(const bf16x8*)tmp;
  }
}

// ---------------- flash attention (v4: cooperative staging + dbuf pipeline) ----
// Block: 4 waves x 32 q-rows = 128 q-rows. KVBLK=64, double-buffered K/V via
// global_load_lds (pre-swizzled source, linear dest). Per-wave P in LDS.
// LDS: 16K (Kx2) + 16K (Vx2) + 16K (P) = 48KB -> 3 blocks/CU capacity.
__global__ __launch_bounds__(256) void attn_kernel(
    const u16* __restrict__ qb, const u16* __restrict__ kb, const u16* __restrict__ vt,
    u16* __restrict__ attn_out)
{
  __shared__ u16 lds_k[2][KVBLK*64];   // [kv][d], swizzled
  __shared__ u16 lds_v[2][64*KVBLK];   // [dh][kv], swizzled
  __shared__ u16 lds_p[4][32*KVBLK];   // per-wave P [qrow][kv], swizzled
  const int tid = threadIdx.x, lane = tid & 63, w = tid >> 6;
  const int bh = blockIdx.y;
  const int q0 = blockIdx.x * 128;
  const size_t kvbase = (size_t)bh * SEQ * HEAD_DIM;
  const size_t vtbase = (size_t)bh * HEAD_DIM * SEQ;
  const int l15 = lane & 15, lq = lane >> 4;

  // Q fragments with softmax scale 0.125 folded in (exact: power of 2)
  bf16x8 qf[2][2];
  #pragma unroll
  for (int mf=0; mf<2; mf++)
    #pragma unroll
    for (int ks=0; ks<2; ks++){
      const u16* g = qb + kvbase + (size_t)(q0 + w*32 + mf*16 + l15)*64 + ks*32 + lq*8;
      bf16x8 v = *(const bf16x8*)g;
      #pragma unroll
      for (int j=0;j<8;j++) ((u16*)&v)[j] = f2bf(bf2f((u16)v[j]) * 0.125f);
      qf[mf][ks] = v;
    }

  float m_s[2][4], l_s[2][4];
  f32x4 o[2][4];
  #pragma unroll
  for (int mf=0;mf<2;mf++)
    #pragma unroll
    for (int r=0;r<4;r++){ m_s[mf][r] = -3.0e38f; l_s[mf][r] = 0.f; }
  #pragma unroll
  for (int mf=0;mf<2;mf++)
    #pragma unroll
    for (int nv=0;nv<4;nv++) o[mf][nv] = (f32x4){0.f,0.f,0.f,0.f};

  auto stage = [&](int buf, int t){
    const int kv0 = t * KVBLK;
    // K tile [64 kv][64 d]: 512 chunks of 16B; source col-group pre-swizzled
    #pragma unroll
    for (int r=0;r<2;r++){
      int idx = tid + r*256;
      int row = idx >> 3, grp = idx & 7;
      const u16* g = kb + kvbase + (size_t)(kv0 + row)*64 + ((grp ^ swz8(row))<<3);
      gld_lds16(g, &lds_k[buf][idx<<3]);
    }
    // vT tile [64 dh][64 kv]
    #pragma unroll
    for (int r=0;r<2;r++){
      int idx = tid + r*256;
      int row = idx >> 3, grp = idx & 7;
      const u16* g = vt + vtbase + (size_t)row*SEQ + kv0 + ((grp ^ swz8(row))<<3);
      gld_lds16(g, &lds_v[buf][idx<<3]);
    }
  };

  stage(0, 0);
  for (int t=0; t<KVTILES; ++t){
    __syncthreads();                       // tile t staged; buf t^1 free
    if (t+1 < KVTILES) stage((t+1)&1, t+1); // overlap with compute(t)
    const int buf = t & 1;

    // ---- S = Q K^T ----
    f32x4 s[2][4];
    #pragma unroll
    for (int mf=0;mf<2;mf++)
      #pragma unroll
      for (int nf=0;nf<4;nf++) s[mf][nf] = (f32x4){0.f,0.f,0.f,0.f};
    __builtin_amdgcn_s_setprio(1);
    #pragma unroll
    for (int ks=0; ks<2; ks++){
      #pragma unroll
      for (int nf=0; nf<4; nf++){
        int rowk = nf*16 + l15;
        int grp = (ks*4 + lq) ^ swz8(rowk);
        bf16x8 kv = *(const bf16x8*)&lds_k[buf][rowk*64 + (grp<<3)];
        s[0][nf] = mfma_bf16(qf[0][0+ks], kv, s[0][nf]);
        s[1][nf] = mfma_bf16(qf[1][0+ks], kv, s[1][nf]);
      }
    }
    __builtin_amdgcn_s_setprio(0);

    // ---- online softmax (row = w*32 + mf*16 + lq*4 + r; 16 lanes per row) ----
    #pragma unroll
    for (int mf=0;mf<2;mf++){
      #pragma unroll
      for (int r=0;r<4;r++){
        float vmax = fmaxf(fmaxf(s[mf][0][r], s[mf][1][r]),
                           fmaxf(s[mf][2][r], s[mf][3][r]));
        vmax = fmaxf(vmax, __shfl_xor(vmax,1));
        vmax = fmaxf(vmax, __shfl_xor(vmax,2));
        vmax = fmaxf(vmax, __shfl_xor(vmax,4));
        vmax = fmaxf(vmax, __shfl_xor(vmax,8));
        float mnew = fmaxf(m_s[mf][r], vmax);
        float c = __expf(m_s[mf][r] - mnew);
        float rsum = 0.f;
        #pragma unroll
        for (int nf=0;nf<4;nf++){
          float p = __expf(s[mf][nf][r] - mnew);
          s[mf][nf][r] = p;
          rsum += p;
        }
        rsum += __shfl_xor(rsum,1);
        rsum += __shfl_xor(rsum,2);
        rsum += __shfl_xor(rsum,4);
        rsum += __shfl_xor(rsum,8);
        l_s[mf][r] = l_s[mf][r]*c + rsum;
        m_s[mf][r] = mnew;
        #pragma unroll
        for (int nv=0;nv<4;nv++) o[mf][nv][r] *= c;
      }
    }

    // ---- P -> per-wave LDS (bf16, swizzled) ----
    #pragma unroll
    for (int mf=0;mf<2;mf++)
      #pragma unroll
      for (int nf=0;nf<4;nf++)
        #pragma unroll
        for (int r=0;r<4;r++){
          int rowp = mf*16 + lq*4 + r;
          int col  = nf*16 + l15;
          int slot = (col>>3) ^ swz8(rowp);
          lds_p[w][rowp*KVBLK + (slot<<3) + (col&7)] = f2bf_fast(s[mf][nf][r]);
        }

    // ---- O += P V ----
    __builtin_amdgcn_s_setprio(1);
    #pragma unroll
    for (int ks=0;ks<2;ks++){
      bf16x8 pa[2];
      #pragma unroll
      for (int mf=0;mf<2;mf++){
        int rowp = mf*16 + l15;
        int grp  = (ks*4 + lq) ^ swz8(rowp);
        pa[mf] = *(const bf16x8*)&lds_p[w][rowp*KVBLK + (grp<<3)];
      }
      #pragma unroll
      for (int nv=0;nv<4;nv++){
        int rowv = nv*16 + l15;
        int grp  = (ks*4 + lq) ^ swz8(rowv);
        bf16x8 vbv = *(const bf16x8*)&lds_v[buf][rowv*KVBLK + (grp<<3)];
        o[0][nv] = mfma_bf16(pa[0], vbv, o[0][nv]);
        o[1][nv] = mfma_bf16(pa[1], vbv, o[1][nv]);
      }
    }
    __builtin_amdgcn_s_setprio(0);
  }

  const int b = bh >> 4, h = bh & 15;
  #pragma unroll
  for (int mf=0;mf<2;mf++){
    #pragma unroll
    for (int r=0;r<4;r++){
      float inv = 1.0f / l_s[mf][r];
      int row = q0 + w*32 + mf*16 + lq*4 + r;
      size_t obase = ((size_t)b*SEQ + row)*D_MODEL + h*64;
      #pragma unroll
      for (int nv=0;nv<4;nv++)
        attn_out[obase + nv*16 + l15] = f2bf(o[mf][nv][r] * inv);
    }
  }
}

// ---------------- host ----------------
extern "C" void kernel_launch(void* const* d_in, const int* in_sizes, int n_in,
                              void* d_out, int out_size, void* d_ws, size_t ws_size,
                              hipStream_t stream){
  const float* x  = (const float*)d_in[0];
  const float* wq = (const float*)d_in[1];
  const float* bq = (const float*)d_in[2];
  const float* wk = (const float*)d_in[3];
  const float* bk = (const float*)d_in[4];
  const float* wv = (const float*)d_in[5];
  const float* bv = (const float*)d_in[6];
  const float* wo = (const float*)d_in[7];
  const float* bo = (const float*)d_in[8];
  const float* gq = (const float*)d_in[9];
  const float* gk = (const float*)d_in[10];
  float* out = (float*)d_out;

  char* ws = (char*)d_ws;
  size_t off = 0;
  auto alloc = [&](size_t bytes) -> char* {
    char* p = ws + off; off += (bytes + 255) & ~(size_t)255; return p;
  };
  const size_t ND = (size_t)MROWS * D_MODEL;       // 4M
  u16* x_hi    = (u16*)alloc(ND*2);
  u16* x_lo    = (u16*)alloc(ND*2);
  u16* wqkv_hi = (u16*)alloc((size_t)3072*1024*2);
  u16* wqkv_lo = (u16*)alloc((size_t)3072*1024*2);
  u16* wo_hi   = (u16*)alloc((size_t)1024*1024*2);
  u16* wo_lo   = (u16*)alloc((size_t)1024*1024*2);
  float* bqkv  = (float*)alloc(3072*4);
  u16* q_bf    = (u16*)alloc(ND*2);
  u16* k_bf    = (u16*)alloc(ND*2);
  u16* v_bf    = (u16*)alloc(ND*2);
  u16* vT      = (u16*)alloc(ND*2);
  u16* attn_bf = (u16*)alloc(ND*2);
  (void)ws_size; (void)in_sizes; (void)n_in; (void)out_size;

  pack_split<<<4096, 256, 0, stream>>>(x,  x_hi, x_lo, (int)(ND/4));
  pack_split<<<1024, 256, 0, stream>>>(wq, wqkv_hi,           wqkv_lo,           262144);
  pack_split<<<1024, 256, 0, stream>>>(wk, wqkv_hi + 1048576, wqkv_lo + 1048576, 262144);
  pack_split<<<1024, 256, 0, stream>>>(wv, wqkv_hi + 2097152, wqkv_lo + 2097152, 262144);
  pack_split<<<1024, 256, 0, stream>>>(wo, wo_hi, wo_lo, 262144);
  pack_bias<<<12, 256, 0, stream>>>(bq, bk, bv, bqkv);

  gemm_bt<3,1><<<dim3(32,24), 256, 0, stream>>>(x_hi, x_lo, wqkv_hi, wqkv_lo, bqkv,
        nullptr, q_bf, k_bf, v_bf, gq, gk, MROWS, 3072, 1024);

  transpose_v<<<1024, 256, 0, stream>>>(v_bf, vT);

  attn_kernel<<<dim3(16,32), 256, 0, stream>>>(q_bf, k_bf, vT, attn_bf);

  gemm_bt<1,0><<<dim3(32,8), 256, 0, stream>>>(attn_bf, nullptr, wo_hi, nullptr, bo,
        out, nullptr, nullptr, nullptr, nullptr, nullptr, MROWS, 1024, 1024);
}

// Round 5
// 193.274 us; speedup vs baseline: 2.0282x; 1.2547x over previous
//
#include <hip/hip_runtime.h>
#include <stdint.h>

#define D_MODEL 1024
#define NHEAD 16
#define HEAD_DIM 64
#define SEQ 2048
#define BATCH 2
#define MROWS (BATCH*SEQ)   // 4096
#define KVBLK 64
#define KVTILES (SEQ/KVBLK) // 32

typedef unsigned short u16;
typedef short bf16x8 __attribute__((ext_vector_type(8)));
typedef float f32x4 __attribute__((ext_vector_type(4)));
typedef float f32x16 __attribute__((ext_vector_type(16)));

__device__ inline float bf2f(u16 h){ return __uint_as_float(((unsigned)h)<<16); }
__device__ inline u16 f2bf(float x){
  unsigned u = __float_as_uint(x);
  unsigned r = (u + 0x7FFFu + ((u>>16)&1u)) >> 16;
  return (u16)r;
}

// Builtin MFMA: compiler inserts MFMA hazard nops/waitcnts (R2 lesson).
__device__ inline f32x4 mfma_bf16(bf16x8 a, bf16x8 b, f32x4 c){
  return __builtin_amdgcn_mfma_f32_16x16x32_bf16(a, b, c, 0, 0, 0);
}
__device__ inline f32x16 mfma32_bf16(bf16x8 a, bf16x8 b, f32x16 c){
  return __builtin_amdgcn_mfma_f32_32x32x16_bf16(a, b, c, 0, 0, 0);
}

__device__ inline void gld_lds16(const u16* g, u16* l){
  __builtin_amdgcn_global_load_lds(
      (const __attribute__((address_space(1))) void*)g,
      (__attribute__((address_space(3))) void*)l, 16, 0, 0);
}

// unified LDS swizzle: distinct per row within 8-row AND across 8-row stripes
__device__ inline int swz8(int row){ return (row ^ (row >> 3)) & 7; }

// pack two f32 -> (bf16(p0) | bf16(p1)<<16), round-half-up (P only)
__device__ inline uint32_t pack_bf2(float p0, float p1){
  uint32_t u0 = __float_as_uint(p0) + 0x8000u;
  uint32_t u1 = __float_as_uint(p1) + 0x8000u;
  return __builtin_amdgcn_perm(u1, u0, 0x07060302u);
}

// ---------------- pack kernels ----------------
__global__ __launch_bounds__(256) void pack_split(const float* __restrict__ src,
                                                  u16* __restrict__ hi, u16* __restrict__ lo, int n4){
  int i = blockIdx.x*256 + threadIdx.x;
  if (i >= n4) return;
  float4 v = ((const float4*)src)[i];
  float vv[4] = {v.x, v.y, v.z, v.w};
  u16 h[4], l[4];
  #pragma unroll
  for (int j=0;j<4;j++){
    h[j] = f2bf(vv[j]);
    l[j] = f2bf(vv[j] - bf2f(h[j]));
  }
  ((ushort4*)hi)[i] = make_ushort4(h[0],h[1],h[2],h[3]);
  ((ushort4*)lo)[i] = make_ushort4(l[0],l[1],l[2],l[3]);
}

__global__ __launch_bounds__(256) void pack_bias(const float* __restrict__ bq, const float* __restrict__ bk,
                                                 const float* __restrict__ bv, float* __restrict__ out){
  int i = blockIdx.x*256 + threadIdx.x;
  if (i < 1024) out[i] = bq[i];
  else if (i < 2048) out[i] = bk[i-1024];
  else if (i < 3072) out[i] = bv[i-2048];
}

// ---------------- GEMM: C = A * B^T (+bias), split-bf16 phases ----------------
template<int PHASES, int MODE>
__global__ __launch_bounds__(256) void gemm_bt(
    const u16* __restrict__ a_hi, const u16* __restrict__ a_lo,
    const u16* __restrict__ b_hi, const u16* __restrict__ b_lo,
    const float* __restrict__ bias,
    float* __restrict__ out_f,
    u16* __restrict__ qb, u16* __restrict__ kb, u16* __restrict__ vb,
    const float* __restrict__ gq, const float* __restrict__ gk,
    int M, int N, int K)
{
  __shared__ u16 lds[2][8192];   // per buf: A[128][32] then B[128][32]
  const int tid = threadIdx.x;
  const int lane = tid & 63;
  const int w = tid >> 6;
  const int wr = w >> 1, wc = w & 1;
  const int m0 = blockIdx.x * 128;
  const int n0 = blockIdx.y * 128;
  const int KS = K / 32;
  const int NT = PHASES * KS;

  f32x4 acc[4][4];
  #pragma unroll
  for (int i=0;i<4;i++)
    #pragma unroll
    for (int j=0;j<4;j++) acc[i][j] = (f32x4){0.f,0.f,0.f,0.f};

  auto stage = [&](int buf, int kt){
    int ph = (PHASES==1) ? 0 : (kt / KS);
    int kk = (PHASES==1 ? kt : (kt % KS)) * 32;
    const u16* As = (ph==1) ? a_lo : a_hi;
    const u16* Bs = (ph==2) ? b_lo : b_hi;
    u16* base = &lds[buf][0];
    #pragma unroll
    for (int r=0;r<2;r++){
      const u16* g = As + (size_t)(m0 + (tid>>2) + r*64)*K + kk + (tid&3)*8;
      gld_lds16(g, base + w*512 + r*2048);
    }
    #pragma unroll
    for (int r=0;r<2;r++){
      const u16* g = Bs + (size_t)(n0 + (tid>>2) + r*64)*K + kk + (tid&3)*8;
      gld_lds16(g, base + 4096 + w*512 + r*2048);
    }
  };

  auto compute = [&](int buf){
    const u16* la = &lds[buf][0];
    const u16* lb = &lds[buf][4096];
    const int koff = (lane>>4)*8;
    const int rowa = wr*64 + (lane&15);
    const int rowb = wc*64 + (lane&15);
    bf16x8 af[4], bfv[4];
    #pragma unroll
    for (int i=0;i<4;i++) af[i]  = *(const bf16x8*)&la[(rowa + i*16)*32 + koff];
    #pragma unroll
    for (int i=0;i<4;i++) bfv[i] = *(const bf16x8*)&lb[(rowb + i*16)*32 + koff];
    #pragma unroll
    for (int i=0;i<4;i++)
      #pragma unroll
      for (int j=0;j<4;j++)
        acc[i][j] = mfma_bf16(af[i], bfv[j], acc[i][j]);
  };

  stage(0, 0);
  for (int kt=0; kt<NT; ++kt){
    __syncthreads();
    if (kt+1 < NT) stage((kt+1)&1, kt+1);
    compute(kt&1);
  }

  const int gcolbase = n0 + wc*64;
  if (MODE == 0){
    #pragma unroll
    for (int j=0;j<4;j++){
      float bj = bias ? bias[gcolbase + j*16 + (lane&15)] : 0.f;
      #pragma unroll
      for (int i=0;i<4;i++){
        int row = m0 + wr*64 + i*16 + (lane>>4)*4;
        #pragma unroll
        for (int r=0;r<4;r++)
          out_f[(size_t)(row+r)*N + gcolbase + j*16 + (lane&15)] = acc[i][j][r] + bj;
      }
    }
  } else {
    const int sidx = gcolbase >> 6;   // 0..47 head-segment
    const int ttype = sidx < 16 ? 0 : (sidx < 32 ? 1 : 2);
    u16* dst = ttype==0 ? qb : (ttype==1 ? kb : vb);
    const int h = sidx - (ttype==1 ? 16 : (ttype==2 ? 32 : 0));
    float gvals[4], bvals[4];
    #pragma unroll
    for (int j=0;j<4;j++){
      int dh = j*16 + (lane&15);
      bvals[j] = bias[gcolbase + dh];
      gvals[j] = ttype==0 ? gq[dh] : (ttype==1 ? gk[dh] : 1.0f);
    }
    #pragma unroll
    for (int i=0;i<4;i++){
      #pragma unroll
      for (int r=0;r<4;r++){
        float tv[4];
        float ssq = 0.f;
        #pragma unroll
        for (int j=0;j<4;j++){ tv[j] = acc[i][j][r] + bvals[j]; ssq += tv[j]*tv[j]; }
        ssq += __shfl_xor(ssq, 1);
        ssq += __shfl_xor(ssq, 2);
        ssq += __shfl_xor(ssq, 4);
        ssq += __shfl_xor(ssq, 8);
        float s = 1.0f;
        if (ttype < 2) s = 1.0f / sqrtf(ssq * (1.0f/64.0f) + 1e-6f);
        int row = m0 + wr*64 + i*16 + (lane>>4)*4 + r;
        int bi = row >> 11, li = row & 2047;
        size_t obase = ((size_t)(bi*NHEAD + h)*SEQ + li)*HEAD_DIM;
        #pragma unroll
        for (int j=0;j<4;j++){
          float val = tv[j] * s * gvals[j];
          float z = rintf(val * 2.0f);           // round-half-even == jnp.round
          z = fminf(8.0f, fmaxf(-8.0f, z));
          dst[obase + j*16 + (lane&15)] = f2bf(z * 0.5f);   // exact in bf16
        }
      }
    }
  }
}

// ---------------- v [B,H,L,64] -> vT [B,H,64,L] ----------------
__global__ __launch_bounds__(256) void transpose_v(const u16* __restrict__ v, u16* __restrict__ vt){
  __shared__ u16 tl[64][66];
  int bh = blockIdx.x >> 5;
  int l0 = (blockIdx.x & 31) * 64;
  int tid = threadIdx.x;
  #pragma unroll
  for (int it=0; it<2; ++it){
    int idx = tid + it*256;
    int row = idx >> 3, g = idx & 7;
    bf16x8 d = *(const bf16x8*)(v + ((size_t)bh*SEQ + l0 + row)*64 + g*8);
    #pragma unroll
    for (int j=0;j<8;j++) tl[row][g*8+j] = (u16)d[j];
  }
  __syncthreads();
  #pragma unroll
  for (int it=0; it<2; ++it){
    int idx = tid + it*256;
    int dh = idx >> 3, g = idx & 7;
    u16 tmp[8];
    #pragma unroll
    for (int j=0;j<8;j++) tmp[j] = tl[g*8+j][dh];
    *(bf16x8*)(vt + ((size_t)bh*HEAD_DIM + dh)*SEQ + l0 + g*8) = *(const bf16x8*)tmp;
  }
}

// ---------------- flash attention (v5: 32x32 swapped-QK, in-register P) ------
// 4 waves x 32 q-rows. KVBLK=64, dbuf K/V staging (32KB LDS). Swapped QK^T:
// lane owns q=lane&31; S C-layout (m74/m101): col=lane&31(q),
// row=(reg&3)+8*(reg>>2)+4*(lane>>5) (kv). Softmax: 31 fmax + 1 shfl_xor(32).
// P stays in registers: pack bf16 pairs + shfl_xor(32) -> PV A-frags (T12).
// Defer-max (T13, THR=8) skips o-rescale on most tiles.
__global__ __launch_bounds__(256) void attn_kernel(
    const u16* __restrict__ qb, const u16* __restrict__ kb, const u16* __restrict__ vt,
    u16* __restrict__ attn_out)
{
  __shared__ u16 lds_k[2][KVBLK*64];   // [kv][d], swizzled
  __shared__ u16 lds_v[2][64*KVBLK];   // [dh][kv], swizzled
  const int tid = threadIdx.x, lane = tid & 63, w = tid >> 6;
  const int bh = blockIdx.y;
  const int q0 = blockIdx.x * 128;
  const size_t kvbase = (size_t)bh * SEQ * HEAD_DIM;
  const size_t vtbase = (size_t)bh * HEAD_DIM * SEQ;
  const int l31 = lane & 31, hi = lane >> 5;

  // Q frags (B operand): Q[q0+w*32+l31][kd*16 + hi*8 + j], scale 0.125 exact
  bf16x8 qf[4];
  #pragma unroll
  for (int kd=0; kd<4; kd++){
    const u16* g = qb + kvbase + (size_t)(q0 + w*32 + l31)*64 + kd*16 + hi*8;
    bf16x8 v = *(const bf16x8*)g;
    #pragma unroll
    for (int j=0;j<8;j++) ((u16*)&v)[j] = f2bf(bf2f((u16)v[j]) * 0.125f);
    qf[kd] = v;
  }

  float m_s = -3.0e38f, l_s = 0.f;
  f32x16 o0, o1;
  #pragma unroll
  for (int r=0;r<16;r++){ o0[r] = 0.f; o1[r] = 0.f; }

  auto stage = [&](int buf, int t){
    const int kv0 = t * KVBLK;
    #pragma unroll
    for (int r=0;r<2;r++){
      int idx = tid + r*256;
      int row = idx >> 3, grp = idx & 7;
      const u16* g = kb + kvbase + (size_t)(kv0 + row)*64 + ((grp ^ swz8(row))<<3);
      gld_lds16(g, &lds_k[buf][idx<<3]);
    }
    #pragma unroll
    for (int r=0;r<2;r++){
      int idx = tid + r*256;
      int row = idx >> 3, grp = idx & 7;
      const u16* g = vt + vtbase + (size_t)row*SEQ + kv0 + ((grp ^ swz8(row))<<3);
      gld_lds16(g, &lds_v[buf][idx<<3]);
    }
  };

  stage(0, 0);
  for (int t=0; t<KVTILES; ++t){
    __syncthreads();                        // tile t staged; buf t^1 free
    if (t+1 < KVTILES) stage((t+1)&1, t+1); // overlap with compute(t)
    const int buf = t & 1;

    // ---- S^T = K Q : s0 = kv 0..31, s1 = kv 32..63 (lane q = l31) ----
    f32x16 s0, s1;
    #pragma unroll
    for (int r=0;r<16;r++){ s0[r] = 0.f; s1[r] = 0.f; }
    __builtin_amdgcn_s_setprio(1);
    #pragma unroll
    for (int kd=0; kd<4; kd++){
      int row0 = l31;
      int row1 = 32 + l31;
      bf16x8 a0 = *(const bf16x8*)&lds_k[buf][row0*64 + (((kd*2+hi) ^ swz8(row0))<<3)];
      bf16x8 a1 = *(const bf16x8*)&lds_k[buf][row1*64 + (((kd*2+hi) ^ swz8(row1))<<3)];
      s0 = mfma32_bf16(a0, qf[kd], s0);
      s1 = mfma32_bf16(a1, qf[kd], s1);
    }
    __builtin_amdgcn_s_setprio(0);

    // ---- softmax for lane's q-row: 31 in-reg fmax + 1 shfl ----
    float pmax = s0[0];
    #pragma unroll
    for (int r=1;r<16;r++) pmax = fmaxf(pmax, s0[r]);
    #pragma unroll
    for (int r=0;r<16;r++) pmax = fmaxf(pmax, s1[r]);
    pmax = fmaxf(pmax, __shfl_xor(pmax, 32));

    if (__any(pmax - m_s > 8.0f)) {         // rescale path (rare after warmup)
      float mnew = fmaxf(m_s, pmax);
      float c = __expf(m_s - mnew);
      m_s = mnew;
      l_s *= c;
      #pragma unroll
      for (int r=0;r<16;r++){
        float cr = __shfl(c, (r&3) + 8*(r>>2) + 4*hi);
        o0[r] *= cr; o1[r] *= cr;
      }
    }

    float rsum = 0.f;
    #pragma unroll
    for (int r=0;r<16;r++){ float p = __expf(s0[r] - m_s); s0[r] = p; rsum += p; }
    #pragma unroll
    for (int r=0;r<16;r++){ float p = __expf(s1[r] - m_s); s1[r] = p; rsum += p; }
    rsum += __shfl_xor(rsum, 32);
    l_s += rsum;

    // ---- P -> bf16 packed words W[kvb][g][i] (g = reg>>2) ----
    uint32_t W[2][4][2];
    #pragma unroll
    for (int g=0; g<4; g++){
      W[0][g][0] = pack_bf2(s0[g*4+0], s0[g*4+1]);
      W[0][g][1] = pack_bf2(s0[g*4+2], s0[g*4+3]);
      W[1][g][0] = pack_bf2(s1[g*4+0], s1[g*4+1]);
      W[1][g][1] = pack_bf2(s1[g*4+2], s1[g*4+3]);
    }
    // ---- assemble PV A-frags in-register: pa[ks] holds P[q=l31][kv=ks*16+hi*8+j]
    bf16x8 pa[4];
    #pragma unroll
    for (int ks=0; ks<4; ks++){
      const int kvb = ks >> 1, ks0 = ks & 1;
      uint32_t own0 = hi ? W[kvb][ks0*2+1][0] : W[kvb][ks0*2][0];
      uint32_t own1 = hi ? W[kvb][ks0*2+1][1] : W[kvb][ks0*2][1];
      uint32_t t0   = hi ? W[kvb][ks0*2][0]   : W[kvb][ks0*2+1][0];
      uint32_t t1   = hi ? W[kvb][ks0*2][1]   : W[kvb][ks0*2+1][1];
      uint32_t sw0  = (uint32_t)__shfl_xor((int)t0, 32);
      uint32_t sw1  = (uint32_t)__shfl_xor((int)t1, 32);
      uint32_t words[4];
      words[0] = hi ? sw0 : own0;
      words[1] = hi ? sw1 : own1;
      words[2] = hi ? own0 : sw0;
      words[3] = hi ? own1 : sw1;
      pa[ks] = *(const bf16x8*)words;
    }

    // ---- O += P V ----
    __builtin_amdgcn_s_setprio(1);
    #pragma unroll
    for (int ks=0; ks<4; ks++){
      int row0 = l31;
      int row1 = 32 + l31;
      bf16x8 vb0 = *(const bf16x8*)&lds_v[buf][row0*64 + (((ks*2+hi) ^ swz8(row0))<<3)];
      bf16x8 vb1 = *(const bf16x8*)&lds_v[buf][row1*64 + (((ks*2+hi) ^ swz8(row1))<<3)];
      o0 = mfma32_bf16(pa[ks], vb0, o0);
      o1 = mfma32_bf16(pa[ks], vb1, o1);
    }
    __builtin_amdgcn_s_setprio(0);
  }

  // ---- epilogue: O[q][dh] = o/l ----
  const int b = bh >> 4, h = bh & 15;
  #pragma unroll
  for (int r=0;r<16;r++){
    int q = (r&3) + 8*(r>>2) + 4*hi;
    float linv = 1.0f / __shfl(l_s, q);
    int row = q0 + w*32 + q;
    size_t obase = ((size_t)b*SEQ + row)*D_MODEL + h*64;
    attn_out[obase + l31]      = f2bf(o0[r] * linv);
    attn_out[obase + 32 + l31] = f2bf(o1[r] * linv);
  }
}

// ---------------- host ----------------
extern "C" void kernel_launch(void* const* d_in, const int* in_sizes, int n_in,
                              void* d_out, int out_size, void* d_ws, size_t ws_size,
                              hipStream_t stream){
  const float* x  = (const float*)d_in[0];
  const float* wq = (const float*)d_in[1];
  const float* bq = (const float*)d_in[2];
  const float* wk = (const float*)d_in[3];
  const float* bk = (const float*)d_in[4];
  const float* wv = (const float*)d_in[5];
  const float* bv = (const float*)d_in[6];
  const float* wo = (const float*)d_in[7];
  const float* bo = (const float*)d_in[8];
  const float* gq = (const float*)d_in[9];
  const float* gk = (const float*)d_in[10];
  float* out = (float*)d_out;

  char* ws = (char*)d_ws;
  size_t off = 0;
  auto alloc = [&](size_t bytes) -> char* {
    char* p = ws + off; off += (bytes + 255) & ~(size_t)255; return p;
  };
  const size_t ND = (size_t)MROWS * D_MODEL;       // 4M
  u16* x_hi    = (u16*)alloc(ND*2);
  u16* x_lo    = (u16*)alloc(ND*2);
  u16* wqkv_hi = (u16*)alloc((size_t)3072*1024*2);
  u16* wqkv_lo = (u16*)alloc((size_t)3072*1024*2);
  u16* wo_hi   = (u16*)alloc((size_t)1024*1024*2);
  u16* wo_lo   = (u16*)alloc((size_t)1024*1024*2);
  float* bqkv  = (float*)alloc(3072*4);
  u16* q_bf    = (u16*)alloc(ND*2);
  u16* k_bf    = (u16*)alloc(ND*2);
  u16* v_bf    = (u16*)alloc(ND*2);
  u16* vT      = (u16*)alloc(ND*2);
  u16* attn_bf = (u16*)alloc(ND*2);
  (void)ws_size; (void)in_sizes; (void)n_in; (void)out_size;

  pack_split<<<4096, 256, 0, stream>>>(x,  x_hi, x_lo, (int)(ND/4));
  pack_split<<<1024, 256, 0, stream>>>(wq, wqkv_hi,           wqkv_lo,           262144);
  pack_split<<<1024, 256, 0, stream>>>(wk, wqkv_hi + 1048576, wqkv_lo + 1048576, 262144);
  pack_split<<<1024, 256, 0, stream>>>(wv, wqkv_hi + 2097152, wqkv_lo + 2097152, 262144);
  pack_split<<<1024, 256, 0, stream>>>(wo, wo_hi, wo_lo, 262144);
  pack_bias<<<12, 256, 0, stream>>>(bq, bk, bv, bqkv);

  gemm_bt<3,1><<<dim3(32,24), 256, 0, stream>>>(x_hi, x_lo, wqkv_hi, wqkv_lo, bqkv,
        nullptr, q_bf, k_bf, v_bf, gq, gk, MROWS, 3072, 1024);

  transpose_v<<<1024, 256, 0, stream>>>(v_bf, vT);

  attn_kernel<<<dim3(16,32), 256, 0, stream>>>(q_bf, k_bf, vT, attn_bf);

  gemm_bt<1,0><<<dim3(32,8), 256, 0, stream>>>(attn_bf, nullptr, wo_hi, nullptr, bo,
        out, nullptr, nullptr, nullptr, nullptr, nullptr, MROWS, 1024, 1024);
}

// Round 6
// 181.402 us; speedup vs baseline: 2.1610x; 1.0654x over previous
//
#include <hip/hip_runtime.h>
#include <stdint.h>

#define D_MODEL 1024
#define NHEAD 16
#define HEAD_DIM 64
#define SEQ 2048
#define BATCH 2
#define MROWS (BATCH*SEQ)   // 4096
#define KVBLK 128
#define KVTILES (SEQ/KVBLK) // 16

typedef unsigned short u16;
typedef short bf16x8 __attribute__((ext_vector_type(8)));
typedef float f32x4 __attribute__((ext_vector_type(4)));
typedef float f32x16 __attribute__((ext_vector_type(16)));

__device__ inline float bf2f(u16 h){ return __uint_as_float(((unsigned)h)<<16); }
__device__ inline u16 f2bf(float x){
  unsigned u = __float_as_uint(x);
  unsigned r = (u + 0x7FFFu + ((u>>16)&1u)) >> 16;
  return (u16)r;
}

// Builtin MFMA: compiler inserts MFMA hazard nops/waitcnts (R2 lesson).
__device__ inline f32x4 mfma_bf16(bf16x8 a, bf16x8 b, f32x4 c){
  return __builtin_amdgcn_mfma_f32_16x16x32_bf16(a, b, c, 0, 0, 0);
}
__device__ inline f32x16 mfma32_bf16(bf16x8 a, bf16x8 b, f32x16 c){
  return __builtin_amdgcn_mfma_f32_32x32x16_bf16(a, b, c, 0, 0, 0);
}

__device__ inline void gld_lds16(const u16* g, u16* l){
  __builtin_amdgcn_global_load_lds(
      (const __attribute__((address_space(1))) void*)g,
      (__attribute__((address_space(3))) void*)l, 16, 0, 0);
}

// unified LDS swizzle: distinct per row within 8-row AND across 8-row stripes
__device__ inline int swz8(int row){ return (row ^ (row >> 3)) & 7; }

// pack two f32 -> (bf16(p0) | bf16(p1)<<16), round-half-up (P only)
__device__ inline uint32_t pack_bf2(float p0, float p1){
  uint32_t u0 = __float_as_uint(p0) + 0x8000u;
  uint32_t u1 = __float_as_uint(p1) + 0x8000u;
  return __builtin_amdgcn_perm(u1, u0, 0x07060302u);
}

// ---------------- pack kernels ----------------
__global__ __launch_bounds__(256) void pack_split(const float* __restrict__ src,
                                                  u16* __restrict__ hi, u16* __restrict__ lo, int n4){
  int i = blockIdx.x*256 + threadIdx.x;
  if (i >= n4) return;
  float4 v = ((const float4*)src)[i];
  float vv[4] = {v.x, v.y, v.z, v.w};
  u16 h[4], l[4];
  #pragma unroll
  for (int j=0;j<4;j++){
    h[j] = f2bf(vv[j]);
    l[j] = f2bf(vv[j] - bf2f(h[j]));
  }
  ((ushort4*)hi)[i] = make_ushort4(h[0],h[1],h[2],h[3]);
  ((ushort4*)lo)[i] = make_ushort4(l[0],l[1],l[2],l[3]);
}

// all 4 weight matrices in one launch (1024 blocks per tensor)
__global__ __launch_bounds__(256) void pack_w(const float* __restrict__ wq, const float* __restrict__ wk,
                                              const float* __restrict__ wv, const float* __restrict__ wo,
                                              u16* __restrict__ qkv_hi, u16* __restrict__ qkv_lo,
                                              u16* __restrict__ wo_hi, u16* __restrict__ wo_lo){
  int which = blockIdx.x >> 10;
  int i = ((blockIdx.x & 1023) << 8) + threadIdx.x;  // float4 idx 0..262143
  const float* src = which==0 ? wq : which==1 ? wk : which==2 ? wv : wo;
  u16* hi = (which==3) ? wo_hi : qkv_hi + ((size_t)which << 20);
  u16* lo = (which==3) ? wo_lo : qkv_lo + ((size_t)which << 20);
  float4 v = ((const float4*)src)[i];
  float vv[4] = {v.x, v.y, v.z, v.w};
  u16 h[4], l[4];
  #pragma unroll
  for (int j=0;j<4;j++){
    h[j] = f2bf(vv[j]);
    l[j] = f2bf(vv[j] - bf2f(h[j]));
  }
  ((ushort4*)hi)[i] = make_ushort4(h[0],h[1],h[2],h[3]);
  ((ushort4*)lo)[i] = make_ushort4(l[0],l[1],l[2],l[3]);
}

__global__ __launch_bounds__(256) void pack_bias(const float* __restrict__ bq, const float* __restrict__ bk,
                                                 const float* __restrict__ bv, float* __restrict__ out){
  int i = blockIdx.x*256 + threadIdx.x;
  if (i < 1024) out[i] = bq[i];
  else if (i < 2048) out[i] = bk[i-1024];
  else if (i < 3072) out[i] = bv[i-2048];
}

// ---------------- fused QKV GEMM ----------------
// acc = x_hi*w_hi^T + x_lo*w_hi^T + x_hi*w_lo^T, phase-fused:
//   steps 0..31:  stage {A_hi, A_lo, B_hi} (24KB/buf) -> 32 MFMA/barrier
//   steps 32..63: stage {A_hi, B_lo}                  -> 16 MFMA/barrier
// LDS 48KB (3 blocks/CU). Epilogue: bias -> RMSNorm(gq/gk) -> SFN -> q/k/v bf16.
__global__ __launch_bounds__(256) void gemm_qkv(
    const u16* __restrict__ a_hi, const u16* __restrict__ a_lo,
    const u16* __restrict__ b_hi, const u16* __restrict__ b_lo,
    const float* __restrict__ bias,
    u16* __restrict__ qb, u16* __restrict__ kb, u16* __restrict__ vb,
    const float* __restrict__ gq, const float* __restrict__ gk)
{
  __shared__ u16 lds[2][12288];   // [0):A_hi [4096):A_lo [8192):B
  const int tid = threadIdx.x;
  const int lane = tid & 63;
  const int w = tid >> 6;
  const int wr = w >> 1, wc = w & 1;
  const int m0 = blockIdx.x * 128;
  const int n0 = blockIdx.y * 128;
  const int K = 1024;

  f32x4 acc[4][4];
  #pragma unroll
  for (int i=0;i<4;i++)
    #pragma unroll
    for (int j=0;j<4;j++) acc[i][j] = (f32x4){0.f,0.f,0.f,0.f};

  auto stage = [&](int buf, int kt){
    u16* base = &lds[buf][0];
    if (kt < 32){
      int kk = kt << 5;
      #pragma unroll
      for (int r=0;r<2;r++){
        const u16* g = a_hi + (size_t)(m0 + (tid>>2) + r*64)*K + kk + (tid&3)*8;
        gld_lds16(g, base + w*512 + r*2048);
      }
      #pragma unroll
      for (int r=0;r<2;r++){
        const u16* g = a_lo + (size_t)(m0 + (tid>>2) + r*64)*K + kk + (tid&3)*8;
        gld_lds16(g, base + 4096 + w*512 + r*2048);
      }
      #pragma unroll
      for (int r=0;r<2;r++){
        const u16* g = b_hi + (size_t)(n0 + (tid>>2) + r*64)*K + kk + (tid&3)*8;
        gld_lds16(g, base + 8192 + w*512 + r*2048);
      }
    } else {
      int kk = (kt-32) << 5;
      #pragma unroll
      for (int r=0;r<2;r++){
        const u16* g = a_hi + (size_t)(m0 + (tid>>2) + r*64)*K + kk + (tid&3)*8;
        gld_lds16(g, base + w*512 + r*2048);
      }
      #pragma unroll
      for (int r=0;r<2;r++){
        const u16* g = b_lo + (size_t)(n0 + (tid>>2) + r*64)*K + kk + (tid&3)*8;
        gld_lds16(g, base + 8192 + w*512 + r*2048);
      }
    }
  };

  const int koff = (lane>>4)*8;
  const int rowa = wr*64 + (lane&15);
  const int rowb = wc*64 + (lane&15);

  stage(0, 0);
  for (int kt=0; kt<64; ++kt){
    __syncthreads();
    if (kt+1 < 64) stage((kt+1)&1, kt+1);
    const u16* la = &lds[kt&1][0];
    const u16* lb = &lds[kt&1][8192];
    bf16x8 bfv[4];
    #pragma unroll
    for (int j=0;j<4;j++) bfv[j] = *(const bf16x8*)&lb[(rowb + j*16)*32 + koff];
    bf16x8 af[4];
    #pragma unroll
    for (int i=0;i<4;i++) af[i] = *(const bf16x8*)&la[(rowa + i*16)*32 + koff];
    #pragma unroll
    for (int i=0;i<4;i++)
      #pragma unroll
      for (int j=0;j<4;j++)
        acc[i][j] = mfma_bf16(af[i], bfv[j], acc[i][j]);
    if (kt < 32){
      const u16* ll = &lds[kt&1][4096];
      bf16x8 al[4];
      #pragma unroll
      for (int i=0;i<4;i++) al[i] = *(const bf16x8*)&ll[(rowa + i*16)*32 + koff];
      #pragma unroll
      for (int i=0;i<4;i++)
        #pragma unroll
        for (int j=0;j<4;j++)
          acc[i][j] = mfma_bf16(al[i], bfv[j], acc[i][j]);
    }
  }

  // ---- epilogue: bias -> RMSNorm -> SFN -> q/k/v [B,H,L,64] bf16 ----
  const int gcolbase = n0 + wc*64;
  const int sidx = gcolbase >> 6;   // 0..47 head-segment
  const int ttype = sidx < 16 ? 0 : (sidx < 32 ? 1 : 2);
  u16* dst = ttype==0 ? qb : (ttype==1 ? kb : vb);
  const int h = sidx - (ttype==1 ? 16 : (ttype==2 ? 32 : 0));
  float gvals[4], bvals[4];
  #pragma unroll
  for (int j=0;j<4;j++){
    int dh = j*16 + (lane&15);
    bvals[j] = bias[gcolbase + dh];
    gvals[j] = ttype==0 ? gq[dh] : (ttype==1 ? gk[dh] : 1.0f);
  }
  #pragma unroll
  for (int i=0;i<4;i++){
    #pragma unroll
    for (int r=0;r<4;r++){
      float tv[4];
      float ssq = 0.f;
      #pragma unroll
      for (int j=0;j<4;j++){ tv[j] = acc[i][j][r] + bvals[j]; ssq += tv[j]*tv[j]; }
      ssq += __shfl_xor(ssq, 1);
      ssq += __shfl_xor(ssq, 2);
      ssq += __shfl_xor(ssq, 4);
      ssq += __shfl_xor(ssq, 8);
      float s = 1.0f;
      if (ttype < 2) s = 1.0f / sqrtf(ssq * (1.0f/64.0f) + 1e-6f);
      int row = m0 + wr*64 + i*16 + (lane>>4)*4 + r;
      int bi = row >> 11, li = row & 2047;
      size_t obase = ((size_t)(bi*NHEAD + h)*SEQ + li)*HEAD_DIM;
      #pragma unroll
      for (int j=0;j<4;j++){
        float val = tv[j] * s * gvals[j];
        float z = rintf(val * 2.0f);           // round-half-even == jnp.round
        z = fminf(8.0f, fmaxf(-8.0f, z));
        dst[obase + j*16 + (lane&15)] = f2bf(z * 0.5f);   // exact in bf16
      }
    }
  }
}

// ---------------- GEMM: C = A * B^T (+bias) fp32 out (out-projection) --------
__global__ __launch_bounds__(256) void gemm_bt(
    const u16* __restrict__ a_hi, const u16* __restrict__ b_hi,
    const float* __restrict__ bias, float* __restrict__ out_f,
    int M, int N, int K)
{
  __shared__ u16 lds[2][8192];
  const int tid = threadIdx.x;
  const int lane = tid & 63;
  const int w = tid >> 6;
  const int wr = w >> 1, wc = w & 1;
  const int m0 = blockIdx.x * 128;
  const int n0 = blockIdx.y * 128;
  const int NT = K / 32;

  f32x4 acc[4][4];
  #pragma unroll
  for (int i=0;i<4;i++)
    #pragma unroll
    for (int j=0;j<4;j++) acc[i][j] = (f32x4){0.f,0.f,0.f,0.f};

  auto stage = [&](int buf, int kt){
    int kk = kt * 32;
    u16* base = &lds[buf][0];
    #pragma unroll
    for (int r=0;r<2;r++){
      const u16* g = a_hi + (size_t)(m0 + (tid>>2) + r*64)*K + kk + (tid&3)*8;
      gld_lds16(g, base + w*512 + r*2048);
    }
    #pragma unroll
    for (int r=0;r<2;r++){
      const u16* g = b_hi + (size_t)(n0 + (tid>>2) + r*64)*K + kk + (tid&3)*8;
      gld_lds16(g, base + 4096 + w*512 + r*2048);
    }
  };

  stage(0, 0);
  for (int kt=0; kt<NT; ++kt){
    __syncthreads();
    if (kt+1 < NT) stage((kt+1)&1, kt+1);
    const u16* la = &lds[kt&1][0];
    const u16* lb = &lds[kt&1][4096];
    const int koff = (lane>>4)*8;
    const int rowa = wr*64 + (lane&15);
    const int rowb = wc*64 + (lane&15);
    bf16x8 af[4], bfv[4];
    #pragma unroll
    for (int i=0;i<4;i++) af[i]  = *(const bf16x8*)&la[(rowa + i*16)*32 + koff];
    #pragma unroll
    for (int i=0;i<4;i++) bfv[i] = *(const bf16x8*)&lb[(rowb + i*16)*32 + koff];
    #pragma unroll
    for (int i=0;i<4;i++)
      #pragma unroll
      for (int j=0;j<4;j++)
        acc[i][j] = mfma_bf16(af[i], bfv[j], acc[i][j]);
  }

  const int gcolbase = n0 + wc*64;
  #pragma unroll
  for (int j=0;j<4;j++){
    float bj = bias[gcolbase + j*16 + (lane&15)];
    #pragma unroll
    for (int i=0;i<4;i++){
      int row = m0 + wr*64 + i*16 + (lane>>4)*4;
      #pragma unroll
      for (int r=0;r<4;r++)
        out_f[(size_t)(row+r)*N + gcolbase + j*16 + (lane&15)] = acc[i][j][r] + bj;
    }
  }
}

// ---------------- v [B,H,L,64] -> vT [B,H,64,L] ----------------
__global__ __launch_bounds__(256) void transpose_v(const u16* __restrict__ v, u16* __restrict__ vt){
  __shared__ u16 tl[64][66];
  int bh = blockIdx.x >> 5;
  int l0 = (blockIdx.x & 31) * 64;
  int tid = threadIdx.x;
  #pragma unroll
  for (int it=0; it<2; ++it){
    int idx = tid + it*256;
    int row = idx >> 3, g = idx & 7;
    bf16x8 d = *(const bf16x8*)(v + ((size_t)bh*SEQ + l0 + row)*64 + g*8);
    #pragma unroll
    for (int j=0;j<8;j++) tl[row][g*8+j] = (u16)d[j];
  }
  __syncthreads();
  #pragma unroll
  for (int it=0; it<2; ++it){
    int idx = tid + it*256;
    int dh = idx >> 3, g = idx & 7;
    u16 tmp[8];
    #pragma unroll
    for (int j=0;j<8;j++) tmp[j] = tl[g*8+j][dh];
    *(bf16x8*)(vt + ((size_t)bh*HEAD_DIM + dh)*SEQ + l0 + g*8) = *(const bf16x8*)tmp;
  }
}

// ---------------- flash attention (v6: KVBLK=128, 2x64 halves) --------------
// 4 waves x 32 q-rows. KVBLK=128 staged dbuf (64KB LDS; grid gives 2 blk/CU
// either way). Inner loop processes two 64-kv halves reusing v5's register
// budget. Swapped QK^T + in-register P (T12) + defer-max (T13).
__global__ __launch_bounds__(256) void attn_kernel(
    const u16* __restrict__ qb, const u16* __restrict__ kb, const u16* __restrict__ vt,
    u16* __restrict__ attn_out)
{
  __shared__ u16 lds_k[2][KVBLK*64];   // [kv][d], swizzled (16KB each)
  __shared__ u16 lds_v[2][64*KVBLK];   // [dh][kv], swizzled (16KB each)
  const int tid = threadIdx.x, lane = tid & 63, w = tid >> 6;
  const int bh = blockIdx.y;
  const int q0 = blockIdx.x * 128;
  const size_t kvbase = (size_t)bh * SEQ * HEAD_DIM;
  const size_t vtbase = (size_t)bh * HEAD_DIM * SEQ;
  const int l31 = lane & 31, hi = lane >> 5;

  // Q frags (B operand): Q[q0+w*32+l31][kd*16 + hi*8 + j], scale 0.125 exact
  bf16x8 qf[4];
  #pragma unroll
  for (int kd=0; kd<4; kd++){
    const u16* g = qb + kvbase + (size_t)(q0 + w*32 + l31)*64 + kd*16 + hi*8;
    bf16x8 v = *(const bf16x8*)g;
    #pragma unroll
    for (int j=0;j<8;j++) ((u16*)&v)[j] = f2bf(bf2f((u16)v[j]) * 0.125f);
    qf[kd] = v;
  }

  float m_s = -3.0e38f, l_s = 0.f;
  f32x16 o0, o1;
  #pragma unroll
  for (int r=0;r<16;r++){ o0[r] = 0.f; o1[r] = 0.f; }

  auto stage = [&](int buf, int t){
    const int kv0 = t * KVBLK;
    #pragma unroll
    for (int r=0;r<4;r++){
      int idx = tid + r*256;
      int row = idx >> 3, grp = idx & 7;          // K: [128 kv][8 grp]
      const u16* g = kb + kvbase + (size_t)(kv0 + row)*64 + ((grp ^ swz8(row))<<3);
      gld_lds16(g, &lds_k[buf][idx<<3]);
    }
    #pragma unroll
    for (int r=0;r<4;r++){
      int idx = tid + r*256;
      int row = idx >> 4, grp = idx & 15;         // V: [64 dh][16 grp]
      const u16* g = vt + vtbase + (size_t)row*SEQ + kv0 + ((grp ^ swz8(row))<<3);
      gld_lds16(g, &lds_v[buf][idx<<3]);
    }
  };

  stage(0, 0);
  for (int t=0; t<KVTILES; ++t){
    __syncthreads();                        // tile t staged; buf t^1 free
    if (t+1 < KVTILES) stage((t+1)&1, t+1); // overlap with compute(t)
    const int buf = t & 1;

    #pragma unroll
    for (int half=0; half<2; ++half){
      // ---- S^T = K Q : s0 = kv 0..31, s1 = kv 32..63 within half ----
      f32x16 s0, s1;
      #pragma unroll
      for (int r=0;r<16;r++){ s0[r] = 0.f; s1[r] = 0.f; }
      const int row0 = half*64 + l31;
      const int row1 = half*64 + 32 + l31;
      __builtin_amdgcn_s_setprio(1);
      #pragma unroll
      for (int kd=0; kd<4; kd++){
        bf16x8 a0 = *(const bf16x8*)&lds_k[buf][row0*64 + (((kd*2+hi) ^ swz8(row0))<<3)];
        bf16x8 a1 = *(const bf16x8*)&lds_k[buf][row1*64 + (((kd*2+hi) ^ swz8(row1))<<3)];
        s0 = mfma32_bf16(a0, qf[kd], s0);
        s1 = mfma32_bf16(a1, qf[kd], s1);
      }
      __builtin_amdgcn_s_setprio(0);

      // ---- softmax for lane's q-row: 31 in-reg fmax + 1 shfl ----
      float pmax = s0[0];
      #pragma unroll
      for (int r=1;r<16;r++) pmax = fmaxf(pmax, s0[r]);
      #pragma unroll
      for (int r=0;r<16;r++) pmax = fmaxf(pmax, s1[r]);
      pmax = fmaxf(pmax, __shfl_xor(pmax, 32));

      if (__any(pmax - m_s > 8.0f)) {       // rescale path (rare after warmup)
        float mnew = fmaxf(m_s, pmax);
        float c = __expf(m_s - mnew);
        m_s = mnew;
        l_s *= c;
        #pragma unroll
        for (int r=0;r<16;r++){
          float cr = __shfl(c, (r&3) + 8*(r>>2) + 4*hi);
          o0[r] *= cr; o1[r] *= cr;
        }
      }

      float rsum = 0.f;
      #pragma unroll
      for (int r=0;r<16;r++){ float p = __expf(s0[r] - m_s); s0[r] = p; rsum += p; }
      #pragma unroll
      for (int r=0;r<16;r++){ float p = __expf(s1[r] - m_s); s1[r] = p; rsum += p; }
      rsum += __shfl_xor(rsum, 32);
      l_s += rsum;

      // ---- P -> bf16 packed words ----
      uint32_t W[2][4][2];
      #pragma unroll
      for (int g=0; g<4; g++){
        W[0][g][0] = pack_bf2(s0[g*4+0], s0[g*4+1]);
        W[0][g][1] = pack_bf2(s0[g*4+2], s0[g*4+3]);
        W[1][g][0] = pack_bf2(s1[g*4+0], s1[g*4+1]);
        W[1][g][1] = pack_bf2(s1[g*4+2], s1[g*4+3]);
      }
      // ---- assemble PV A-frags in-register ----
      bf16x8 pa[4];
      #pragma unroll
      for (int ks=0; ks<4; ks++){
        const int kvb = ks >> 1, ks0 = ks & 1;
        uint32_t own0 = hi ? W[kvb][ks0*2+1][0] : W[kvb][ks0*2][0];
        uint32_t own1 = hi ? W[kvb][ks0*2+1][1] : W[kvb][ks0*2][1];
        uint32_t t0   = hi ? W[kvb][ks0*2][0]   : W[kvb][ks0*2+1][0];
        uint32_t t1   = hi ? W[kvb][ks0*2][1]   : W[kvb][ks0*2+1][1];
        uint32_t sw0  = (uint32_t)__shfl_xor((int)t0, 32);
        uint32_t sw1  = (uint32_t)__shfl_xor((int)t1, 32);
        uint32_t words[4];
        words[0] = hi ? sw0 : own0;
        words[1] = hi ? sw1 : own1;
        words[2] = hi ? own0 : sw0;
        words[3] = hi ? own1 : sw1;
        pa[ks] = *(const bf16x8*)words;
      }

      // ---- O += P V ----
      __builtin_amdgcn_s_setprio(1);
      #pragma unroll
      for (int ks=0; ks<4; ks++){
        const int rv0 = l31, rv1 = 32 + l31;
        const int cg = half*8 + ks*2 + hi;
        bf16x8 vb0 = *(const bf16x8*)&lds_v[buf][rv0*KVBLK + ((cg ^ swz8(rv0))<<3)];
        bf16x8 vb1 = *(const bf16x8*)&lds_v[buf][rv1*KVBLK + ((cg ^ swz8(rv1))<<3)];
        o0 = mfma32_bf16(pa[ks], vb0, o0);
        o1 = mfma32_bf16(pa[ks], vb1, o1);
      }
      __builtin_amdgcn_s_setprio(0);
    }
  }

  // ---- epilogue: O[q][dh] = o/l ----
  const int b = bh >> 4, h = bh & 15;
  #pragma unroll
  for (int r=0;r<16;r++){
    int q = (r&3) + 8*(r>>2) + 4*hi;
    float linv = 1.0f / __shfl(l_s, q);
    int row = q0 + w*32 + q;
    size_t obase = ((size_t)b*SEQ + row)*D_MODEL + h*64;
    attn_out[obase + l31]      = f2bf(o0[r] * linv);
    attn_out[obase + 32 + l31] = f2bf(o1[r] * linv);
  }
}

// ---------------- host ----------------
extern "C" void kernel_launch(void* const* d_in, const int* in_sizes, int n_in,
                              void* d_out, int out_size, void* d_ws, size_t ws_size,
                              hipStream_t stream){
  const float* x  = (const float*)d_in[0];
  const float* wq = (const float*)d_in[1];
  const float* bq = (const float*)d_in[2];
  const float* wk = (const float*)d_in[3];
  const float* bk = (const float*)d_in[4];
  const float* wv = (const float*)d_in[5];
  const float* bv = (const float*)d_in[6];
  const float* wo = (const float*)d_in[7];
  const float* bo = (const float*)d_in[8];
  const float* gq = (const float*)d_in[9];
  const float* gk = (const float*)d_in[10];
  float* out = (float*)d_out;

  char* ws = (char*)d_ws;
  size_t off = 0;
  auto alloc = [&](size_t bytes) -> char* {
    char* p = ws + off; off += (bytes + 255) & ~(size_t)255; return p;
  };
  const size_t ND = (size_t)MROWS * D_MODEL;       // 4M
  u16* x_hi    = (u16*)alloc(ND*2);
  u16* x_lo    = (u16*)alloc(ND*2);
  u16* wqkv_hi = (u16*)alloc((size_t)3072*1024*2);
  u16* wqkv_lo = (u16*)alloc((size_t)3072*1024*2);
  u16* wo_hi   = (u16*)alloc((size_t)1024*1024*2);
  u16* wo_lo   = (u16*)alloc((size_t)1024*1024*2);
  float* bqkv  = (float*)alloc(3072*4);
  u16* q_bf    = (u16*)alloc(ND*2);
  u16* k_bf    = (u16*)alloc(ND*2);
  u16* v_bf    = (u16*)alloc(ND*2);
  u16* vT      = (u16*)alloc(ND*2);
  u16* attn_bf = (u16*)alloc(ND*2);
  (void)ws_size; (void)in_sizes; (void)n_in; (void)out_size;

  pack_split<<<4096, 256, 0, stream>>>(x, x_hi, x_lo, (int)(ND/4));
  pack_w<<<4096, 256, 0, stream>>>(wq, wk, wv, wo, wqkv_hi, wqkv_lo, wo_hi, wo_lo);
  pack_bias<<<12, 256, 0, stream>>>(bq, bk, bv, bqkv);

  gemm_qkv<<<dim3(32,24), 256, 0, stream>>>(x_hi, x_lo, wqkv_hi, wqkv_lo, bqkv,
        q_bf, k_bf, v_bf, gq, gk);

  transpose_v<<<1024, 256, 0, stream>>>(v_bf, vT);

  attn_kernel<<<dim3(16,32), 256, 0, stream>>>(q_bf, k_bf, vT, attn_bf);

  gemm_bt<<<dim3(32,8), 256, 0, stream>>>(attn_bf, wo_hi, bo, out, MROWS, 1024, 1024);
}